// Round 2
// baseline (3320.097 us; speedup 1.0000x reference)
//
#include <hip/hip_runtime.h>
#include <hip/hip_bf16.h>

#define N_NODES   100000
#define N_EDGES   1000000
#define N_PAIRS   2000000
#define IN_CH     64
#define OUT_CH    64
#define NODE_DIM  37
#define STATE_DIM 5
#define FEAT_DIM  106   // IN_CH + NODE_DIM + STATE_DIM

// ---------------------------------------------------------------------------
// Pair kernel: one WAVE per pair k. Lane c owns output channel c and holds
// W_edge[c][:] (106 fp32) in registers (loaded once per persistent block).
// feat components are fetched with wave-uniform addresses (k is uniform within
// the wave), so each load is a single broadcast transaction (compiler may
// scalarize to s_load via the readfirstlane hint). No LDS anywhere: the
// LDS-broadcast alternative is ~6x LDS-pipe-bound (4 FMAs per 12-cyc b128 on
// one pipe/CU vs 4 SIMDs of FMA).
//   h[c] = elu(sum_j W[c][j]*feat[j] + b[c]);  atomicAdd(acc[seg - lo][c], h)
// ---------------------------------------------------------------------------
__global__ __launch_bounds__(256) void pair_kernel(
    const float* __restrict__ x,     // [N_NODES, 37]
    const float* __restrict__ gs,    // [N_NODES, 5]
    const float* __restrict__ ea,    // [N_EDGES, 64]
    const float* __restrict__ W,     // [64, 106]
    const float* __restrict__ b,     // [64]
    const int* __restrict__ aidx,    // [2, N_PAIRS]
    const int* __restrict__ eidx,    // [2, N_PAIRS]
    float* __restrict__ acc,         // [seg_hi-seg_lo, 64] fp32
    int seg_lo, int seg_hi)
{
    const int t    = threadIdx.x;
    const int wave = t >> 6;
    const int lane = t & 63;

    float wrow[FEAT_DIM];
    #pragma unroll
    for (int j = 0; j < FEAT_DIM; ++j)
        wrow[j] = W[lane * FEAT_DIM + j];
    const float bias = b[lane];

    const int stride = gridDim.x * 4;
    for (int k = blockIdx.x * 4 + wave; k < N_PAIRS; k += stride) {
        const int seg = __builtin_amdgcn_readfirstlane(eidx[k]);          // e_idx[0][k]
        if (seg < seg_lo || seg >= seg_hi) continue;                      // wave-uniform branch
        const int e2 = __builtin_amdgcn_readfirstlane(eidx[N_PAIRS + k]); // e_idx[1][k]
        const int a0 = __builtin_amdgcn_readfirstlane(aidx[k]);           // atom_index[0][k]

        const float4* er = (const float4*)(ea + (size_t)e2 * IN_CH); // 256B-aligned rows
        const float*  xr = x  + (size_t)a0 * NODE_DIM;               // 4B-aligned rows
        const float*  gr = gs + (size_t)a0 * STATE_DIM;

        float s0 = bias, s1 = 0.f, s2 = 0.f, s3 = 0.f;
        #pragma unroll
        for (int q = 0; q < IN_CH / 4; ++q) {       // 16 uniform float4 loads
            const float4 f = er[q];
            s0 = fmaf(wrow[4 * q + 0], f.x, s0);
            s1 = fmaf(wrow[4 * q + 1], f.y, s1);
            s2 = fmaf(wrow[4 * q + 2], f.z, s2);
            s3 = fmaf(wrow[4 * q + 3], f.w, s3);
        }
        #pragma unroll
        for (int j = 0; j < NODE_DIM; ++j)          // 37 uniform scalar loads
            s0 = fmaf(wrow[IN_CH + j], xr[j], s0);
        #pragma unroll
        for (int j = 0; j < STATE_DIM; ++j)         // 5 uniform scalar loads
            s1 = fmaf(wrow[IN_CH + NODE_DIM + j], gr[j], s1);

        const float s = (s0 + s1) + (s2 + s3);
        const float h = (s > 0.f) ? s : expm1f(s);
        atomicAdd(&acc[(size_t)(seg - seg_lo) * OUT_CH + lane], h);
    }
}

// ---------------------------------------------------------------------------
// Final kernel: out[e][c] = elu(W_e[c] . edge_attr[e] + b_e[c]) + acc[e-lo][c]
// One wave per edge, lane c = channel c; same register-W + uniform-load shape.
// Memory-bound: streams ea + acc + out (~768 MB total over all windows).
// ---------------------------------------------------------------------------
__global__ __launch_bounds__(256) void final_kernel(
    const float* __restrict__ ea,    // [N_EDGES, 64]
    const float* __restrict__ We,    // [64, 64]
    const float* __restrict__ be,    // [64]
    const float* __restrict__ acc,   // [e_hi-e_lo, 64]
    float* __restrict__ out,         // [N_EDGES, 64]
    int e_lo, int e_hi)
{
    const int t    = threadIdx.x;
    const int wave = t >> 6;
    const int lane = t & 63;

    float wrow[IN_CH];
    #pragma unroll
    for (int j = 0; j < IN_CH; ++j)
        wrow[j] = We[lane * IN_CH + j];
    const float bias = be[lane];

    const int stride = gridDim.x * 4;
    for (int e = e_lo + blockIdx.x * 4 + wave; e < e_hi; e += stride) {
        const float4* er = (const float4*)(ea + (size_t)e * IN_CH);
        float s0 = bias, s1 = 0.f, s2 = 0.f, s3 = 0.f;
        #pragma unroll
        for (int q = 0; q < IN_CH / 4; ++q) {
            const float4 f = er[q];
            s0 = fmaf(wrow[4 * q + 0], f.x, s0);
            s1 = fmaf(wrow[4 * q + 1], f.y, s1);
            s2 = fmaf(wrow[4 * q + 2], f.z, s2);
            s3 = fmaf(wrow[4 * q + 3], f.w, s3);
        }
        const float s = (s0 + s1) + (s2 + s3);
        const float h = (s > 0.f) ? s : expm1f(s);
        out[(size_t)e * OUT_CH + lane] =
            h + acc[(size_t)(e - e_lo) * OUT_CH + lane];
    }
}

extern "C" void kernel_launch(void* const* d_in, const int* in_sizes, int n_in,
                              void* d_out, int out_size, void* d_ws, size_t ws_size,
                              hipStream_t stream) {
    const float* x    = (const float*)d_in[0];
    const float* gs   = (const float*)d_in[1];
    const float* ea   = (const float*)d_in[2];
    const float* W    = (const float*)d_in[3];
    const float* b    = (const float*)d_in[4];
    const float* We   = (const float*)d_in[5];
    const float* be   = (const float*)d_in[6];
    const int*   aidx = (const int*)d_in[7];
    const int*   eidx = (const int*)d_in[8];
    float* out = (float*)d_out;
    float* acc = (float*)d_ws;

    // fp32 segment-sum accumulator lives in d_ws. If ws_size can't hold all
    // 1M x 64 fp32 rows, process segments in windows (same work every call:
    // window count depends only on the constant ws_size).
    const size_t row_bytes = OUT_CH * sizeof(float);
    const size_t need = (size_t)N_EDGES * row_bytes;
    size_t cap = ws_size < need ? ws_size : need;
    int win = (int)(cap / row_bytes);
    if (win < 1) win = 1;

    for (int lo = 0; lo < N_EDGES; lo += win) {
        int hi = lo + win;
        if (hi > N_EDGES) hi = N_EDGES;
        hipMemsetAsync(acc, 0, (size_t)(hi - lo) * row_bytes, stream);
        pair_kernel<<<2048, 256, 0, stream>>>(x, gs, ea, W, b, aidx, eidx,
                                              acc, lo, hi);
        final_kernel<<<2048, 256, 0, stream>>>(ea, We, be, acc, out, lo, hi);
    }
}